// Round 6
// baseline (231.619 us; speedup 1.0000x reference)
//
#include <hip/hip_runtime.h>
#include <stdint.h>

// SIREN batched MLP, MI355X/gfx950 — round 17: per-c epi/MFMA skew, all layers.
// r16 measured: 175 us, MfmaUtil 45-47, VALUBusy 60-63 (sum 107%), absmax
// bit-identical. Pipes: VALU~108us, LDS~85-115us, MFMA~79us; wall 175 >>
// max-pipe 115 -> ~60us intra-wave serialization in the chain
// mfma->epi(serial)->mfma. r16's one fused boundary (L1->L2 per c-chunk) is
// where the gain came from; r17 extends that skew to L2->L3, L3->L4, L4->L5:
// epi computes chunk c's 16 sins, then MFMA chunk c issues while chunk c+1's
// sins interleave (independent ops, same basic block).
// Sin order + per-acc MFMA order UNCHANGED -> absmax must stay 0.006347656.
// Numerics: L1 fp32+split, L2 3-term, L3/L4/L5 hi-only RTE, omega folded into
// staged W1..W4/b1..b4, pkrtz only where lo captures residual.

typedef _Float16 f16x8 __attribute__((ext_vector_type(8)));
typedef __fp16 h16x2 __attribute__((ext_vector_type(2)));   // cvt_pkrtz return type
typedef float f32x4 __attribute__((ext_vector_type(4)));

#define MFMA16 __builtin_amdgcn_mfma_f32_16x16x32_f16

#define B_ 32
#define N_ 32768
#define NTHR 1024
#define NWAVE 16
#define OMEGA_SC 4.77464829275686f   /* 30 / (2*pi) */

// flat param offsets (floats)
#define OFF_W1 0
#define OFF_B1 256
#define OFF_W2 384
#define OFF_B2 16768
#define OFF_W3 16896
#define OFF_B3 33280
#define OFF_W4 33408
#define OFF_B4 49792
#define OFF_W5 49920
#define OFF_B5 50304
#define NPARAM 50307

// LDS image offsets (bytes). A-frag images: [c][mt][lane]*16B.
#define WO_L2H 0
#define WO_W2L 32768
#define WO_L3H 65536
#define WO_L4H 98304
#define WO_L5H 131072      /* 4 KB: single M-tile, rows 3..15 zero */
#define WO_W1X 135168      /* 128 floats, slot-ordered s = c*32 + k_local */
#define WO_W1Y 135680
#define WO_B1S 136192
#define LDS_BIAS 136704    /* 3*128 floats */
#define LDSSET 138240

// args arrive pre-scaled by OMEGA_SC; sine needs only fract + v_sin
__device__ __forceinline__ float sin_rev(float t) {
    return __builtin_amdgcn_sinf(__builtin_amdgcn_fractf(t));
}

__device__ __forceinline__ uint32_t pack2(_Float16 a, _Float16 b) {
    union { _Float16 h[2]; uint32_t u; } x;
    x.h[0] = a; x.h[1] = b;
    return x.u;
}

// sin pair -> hi/lo split packed via pkrtz (lo captures RTZ residual exactly)
__device__ __forceinline__ void sin_split_pk(float a0, float a1,
                                             uint32_t& hw, uint32_t& lw) {
    float s0 = sin_rev(a0), s1 = sin_rev(a1);
    union { h16x2 v; uint32_t u; } x, y;
    x.v = __builtin_amdgcn_cvt_pkrtz(s0, s1);
    float l0 = s0 - (float)x.v[0], l1 = s1 - (float)x.v[1];
    y.v = __builtin_amdgcn_cvt_pkrtz(l0, l1);
    hw = x.u; lw = y.u;
}

// ---------------------------------------------------------------------------
// Main: 1024 threads = 16 waves = 4 waves/SIMD, 1 block/CU (135 KB LDS).
// Phase 0 (fused prep): build LDS weight images directly from p, pre-scaled
//   by OMEGA_SC for the sine layers (W1..W4, b1..b4); W5/b5 unscaled.
//   16x16x32 A-frag: lane l holds A[m=16mt+(l&15)][k_local=8*(l>>4)+e];
//   feature f = 16c + 64*(e>=4) + 4g + (e&3). W2 stored hi+lo; W3/4/5 hi only.
// Phase 1: block covers a 4096-pt slab = 128 32-pt tiles; wave w takes tiles
//   w, w+16, ... (8 tiles each). Grid (32 batches, 8 slabs).
// ---------------------------------------------------------------------------
__global__ __launch_bounds__(NTHR, 4)
void siren_main(const float* __restrict__ xg,
                const float* __restrict__ pg,
                float* __restrict__ out) {
    extern __shared__ __align__(16) char smem[];

    const int t = threadIdx.x;
    const int b = blockIdx.x;
    const int grp = blockIdx.y;
    const float* p = pg + (size_t)b * NPARAM;

    // ---- fused prep: 102 u-slots x 64 lanes = 6528 items, wave-uniform u ----
    for (int it = t; it < 6528; it += NTHR) {
        const int u = it >> 6, l = it & 63;
        if (u < 100) {
            int li, c, mt;
            if (u < 96) { li = u >> 5; int r = u & 31; c = r >> 3; mt = r & 7; }
            else        { li = 3; c = u - 96; mt = 0; }
            const int m = l & 15, gA = l >> 4;
            int wOff; size_t dstH; bool lo = false;
            if (li == 0)      { wOff = OFF_W2; dstH = WO_L2H; lo = true; }
            else if (li == 1) { wOff = OFF_W3; dstH = WO_L3H; }
            else if (li == 2) { wOff = OFF_W4; dstH = WO_L4H; }
            else              { wOff = OFF_W5; dstH = WO_L5H; }
            const int j = (li == 3) ? m : (16 * mt + m);
            const int f0 = 16 * c + 4 * gA;
            const float sc = (li == 3) ? 1.0f : OMEGA_SC;   // W5 feeds no sine

            float v[8];
            if (li == 3 && m >= 3) {
#pragma unroll
                for (int e = 0; e < 8; ++e) v[e] = 0.f;
            } else {
                float4 a  = *(const float4*)(p + wOff + j * 128 + f0);
                float4 bq = *(const float4*)(p + wOff + j * 128 + f0 + 64);
                v[0] = sc * a.x;  v[1] = sc * a.y;  v[2] = sc * a.z;  v[3] = sc * a.w;
                v[4] = sc * bq.x; v[5] = sc * bq.y; v[6] = sc * bq.z; v[7] = sc * bq.w;
            }
            f16x8 hv, lv;
#pragma unroll
            for (int e = 0; e < 8; ++e) {
                _Float16 hh = (_Float16)v[e];
                hv[e] = hh;
                lv[e] = (_Float16)(v[e] - (float)hh);
            }
            size_t idx = (li == 3) ? (size_t)(c * 64 + l) * 16
                                   : (size_t)((c * 8 + mt) * 64 + l) * 16;
            *(f16x8*)(smem + dstH + idx) = hv;
            if (lo) *(f16x8*)(smem + WO_W2L + idx) = lv;
        } else {
            int s = ((u - 100) << 6) + l;      // 0..127
            int c = s >> 5, k = s & 31, gq = k >> 3, e = k & 7;
            int f = 16 * c + ((e & 4) ? 64 : 0) + 4 * gq + (e & 3);
            ((float*)(smem + WO_W1X))[s] = OMEGA_SC * p[OFF_W1 + 2 * f];
            ((float*)(smem + WO_W1Y))[s] = OMEGA_SC * p[OFF_W1 + 2 * f + 1];
            ((float*)(smem + WO_B1S))[s] = OMEGA_SC * p[OFF_B1 + f];
        }
    }
    float* sB = (float*)(smem + LDS_BIAS);
    if (t < 384) {
        int li = t >> 7, f = t & 127;
        sB[t] = OMEGA_SC * p[(li == 0 ? OFF_B2 : li == 1 ? OFF_B3 : OFF_B4) + f];
    }
    const float b5_0 = p[OFF_B5], b5_1 = p[OFF_B5 + 1], b5_2 = p[OFF_B5 + 2];
    __syncthreads();

    const int lane = t & 63;
    const int wv = t >> 6;          // 0..15
    const int n = lane & 15;
    const int g = lane >> 4;
    const int lb = lane * 16;

    const char* L2Hp = smem + WO_L2H;
    const char* W2Lp = smem + WO_W2L;
    const char* L3Hp = smem + WO_L3H;
    const char* L4Hp = smem + WO_L4H;
    const char* L5Hp = smem + WO_L5H;
    const float* W1X = (const float*)(smem + WO_W1X);
    const float* W1Y = (const float*)(smem + WO_W1Y);
    const float* B1S = (const float*)(smem + WO_B1S);

    union UF { f16x8 v; uint32_t w[4]; };

    auto initb2 = [&](f32x4 (&A)[2][8], int li) {
#pragma unroll
        for (int mt = 0; mt < 8; ++mt) {
            f32x4 bb = *(const f32x4*)&sB[li * 128 + 16 * mt + 4 * g];
            A[0][mt] = bb;
            A[1][mt] = bb;
        }
    };

    // per-chunk epilogue: chunk c of acc -> B-frag (16 sins, both pp).
    // RTE converts (hi-only: RTZ bias would inject sign-correlated error).
    auto epi_c = [&](const f32x4 (&A)[2][8], int c, UF (&Xh)[2]) {
#pragma unroll
        for (int pp = 0; pp < 2; ++pp) {
            _Float16 hh[8];
#pragma unroll
            for (int r = 0; r < 4; ++r) {
                hh[r]     = (_Float16)sin_rev(A[pp][c][r]);
                hh[4 + r] = (_Float16)sin_rev(A[pp][c + 4][r]);
            }
            Xh[pp].w[0] = pack2(hh[0], hh[1]); Xh[pp].w[1] = pack2(hh[2], hh[3]);
            Xh[pp].w[2] = pack2(hh[4], hh[5]); Xh[pp].w[3] = pack2(hh[6], hh[7]);
        }
    };

#pragma unroll 1
    for (int tile = wv; tile < 128; tile += NWAVE) {
        asm volatile("" ::: "memory");   // block cross-iter LDS-load hoisting

        const int ptb = grp * 4096 + tile * 32;
        const float2 xy0 = ((const float2*)xg)[(size_t)b * N_ + ptb + n];
        const float2 xy1 = ((const float2*)xg)[(size_t)b * N_ + ptb + 16 + n];

        // ---- L1+L2 fused per c-chunk (r16): produce X1h/l[.][c], consume in
        //      L2 c-pass; L1(c+1) VALU interleaves with in-flight MFMA(c).
        f32x4 A2[2][8];
        initb2(A2, 0);
#pragma unroll
        for (int c = 0; c < 4; ++c) {
            UF X1h[2], X1l[2];
            {
                const int s0 = c * 32 + g * 8;
                float4 wxa = *(const float4*)(W1X + s0), wxb = *(const float4*)(W1X + s0 + 4);
                float4 wya = *(const float4*)(W1Y + s0), wyb = *(const float4*)(W1Y + s0 + 4);
                float4 bba = *(const float4*)(B1S + s0), bbb = *(const float4*)(B1S + s0 + 4);
                float wx[8] = {wxa.x, wxa.y, wxa.z, wxa.w, wxb.x, wxb.y, wxb.z, wxb.w};
                float wy[8] = {wya.x, wya.y, wya.z, wya.w, wyb.x, wyb.y, wyb.z, wyb.w};
                float bc[8] = {bba.x, bba.y, bba.z, bba.w, bbb.x, bbb.y, bbb.z, bbb.w};
#pragma unroll
                for (int pp = 0; pp < 2; ++pp) {
                    const float px = pp ? xy1.x : xy0.x;
                    const float py = pp ? xy1.y : xy0.y;
                    float a[8];
#pragma unroll
                    for (int e = 0; e < 8; ++e)
                        a[e] = fmaf(px, wx[e], fmaf(py, wy[e], bc[e]));
                    sin_split_pk(a[0], a[1], X1h[pp].w[0], X1l[pp].w[0]);
                    sin_split_pk(a[2], a[3], X1h[pp].w[1], X1l[pp].w[1]);
                    sin_split_pk(a[4], a[5], X1h[pp].w[2], X1l[pp].w[2]);
                    sin_split_pk(a[6], a[7], X1h[pp].w[3], X1l[pp].w[3]);
                }
            }
            __builtin_amdgcn_s_setprio(1);
#pragma unroll
            for (int mt = 0; mt < 8; ++mt) {
                f16x8 ah = *(const f16x8*)(L2Hp + (c * 8 + mt) * 1024 + lb);
                f16x8 al = *(const f16x8*)(W2Lp + (c * 8 + mt) * 1024 + lb);
#pragma unroll
                for (int pp = 0; pp < 2; ++pp) {
                    A2[pp][mt] = MFMA16(ah, X1h[pp].v, A2[pp][mt], 0, 0, 0);
                    A2[pp][mt] = MFMA16(ah, X1l[pp].v, A2[pp][mt], 0, 0, 0);
                    A2[pp][mt] = MFMA16(al, X1h[pp].v, A2[pp][mt], 0, 0, 0);
                }
            }
            __builtin_amdgcn_s_setprio(0);
        }

        // ---- L3 with per-c skew: epi2(c) feeds MFMA chunk c; epi2(c+1)
        //      interleaves with MFMA(c) (independent, same basic block).
        f32x4 A3[2][8];
        initb2(A3, 1);
        {
            UF Xc[2];
            epi_c(A2, 0, Xc);
#pragma unroll
            for (int c = 0; c < 4; ++c) {
                __builtin_amdgcn_s_setprio(1);
#pragma unroll
                for (int mt = 0; mt < 8; ++mt) {
                    f16x8 ah = *(const f16x8*)(L3Hp + (c * 8 + mt) * 1024 + lb);
#pragma unroll
                    for (int pp = 0; pp < 2; ++pp)
                        A3[pp][mt] = MFMA16(ah, Xc[pp].v, A3[pp][mt], 0, 0, 0);
                }
                __builtin_amdgcn_s_setprio(0);
                if (c < 3) epi_c(A2, c + 1, Xc);
            }
        }

        // ---- L4 with per-c skew
        f32x4 A4[2][8];
        initb2(A4, 2);
        {
            UF Xc[2];
            epi_c(A3, 0, Xc);
#pragma unroll
            for (int c = 0; c < 4; ++c) {
                __builtin_amdgcn_s_setprio(1);
#pragma unroll
                for (int mt = 0; mt < 8; ++mt) {
                    f16x8 ah = *(const f16x8*)(L4Hp + (c * 8 + mt) * 1024 + lb);
#pragma unroll
                    for (int pp = 0; pp < 2; ++pp)
                        A4[pp][mt] = MFMA16(ah, Xc[pp].v, A4[pp][mt], 0, 0, 0);
                }
                __builtin_amdgcn_s_setprio(0);
                if (c < 3) epi_c(A3, c + 1, Xc);
            }
        }

        // ---- L5 with per-c skew (unscaled weights)
        f32x4 a5[2] = {{0.f, 0.f, 0.f, 0.f}, {0.f, 0.f, 0.f, 0.f}};
        {
            UF Xc[2];
            epi_c(A4, 0, Xc);
#pragma unroll
            for (int c = 0; c < 4; ++c) {
                __builtin_amdgcn_s_setprio(1);
                f16x8 ah = *(const f16x8*)(L5Hp + c * 1024 + lb);
#pragma unroll
                for (int pp = 0; pp < 2; ++pp)
                    a5[pp] = MFMA16(ah, Xc[pp].v, a5[pp], 0, 0, 0);
                __builtin_amdgcn_s_setprio(0);
                if (c < 3) epi_c(A4, c + 1, Xc);
            }
        }

        if (g == 0) {   // rows 0..2 = outputs j=0..2 for point n
#pragma unroll
            for (int pp = 0; pp < 2; ++pp) {
                size_t o = ((size_t)b * N_ + ptb + pp * 16 + n) * 3;
                out[o]     = a5[pp][0] + b5_0;
                out[o + 1] = a5[pp][1] + b5_1;
                out[o + 2] = a5[pp][2] + b5_2;
            }
        }
    }
}

extern "C" void kernel_launch(void* const* d_in, const int* in_sizes, int n_in,
                              void* d_out, int out_size, void* d_ws, size_t ws_size,
                              hipStream_t stream) {
    (void)in_sizes; (void)n_in; (void)out_size; (void)d_ws; (void)ws_size;
    const float* x = (const float*)d_in[0];
    const float* p = (const float*)d_in[1];
    float* o = (float*)d_out;

    // Raise the dynamic-LDS cap exactly once (not per graph-capture pass).
    static bool attr_done = false;
    if (!attr_done) {
        (void)hipFuncSetAttribute(reinterpret_cast<const void*>(siren_main),
                                  hipFuncAttributeMaxDynamicSharedMemorySize, LDSSET);
        attr_done = true;
    }
    siren_main<<<dim3(32, 8), NTHR, LDSSET, stream>>>(x, p, o);
}

// Round 7
// 205.579 us; speedup vs baseline: 1.1267x; 1.1267x over previous
//
#include <hip/hip_runtime.h>
#include <stdint.h>

// SIREN batched MLP, MI355X/gfx950 — round 18: r16 revert + defract + debarrier.
// r17 (per-c epi skew) REGRESSED 175->182: hand-skew + 4x setprio toggles beat
// the compiler's own interleave (m141 lesson). Reverted to r16 structure.
// New model: VALUBusy includes MFMA on CDNA -> no pipe >108us busy vs wall 175
// -> latency/dependency-stall regime, occupancy capped (1024 thr, 135K LDS).
// r18 cuts chain length + enables cross-iter overlap:
//  (1) drop v_fract: v_sin_f32 HW-reduces, domain +-256 >> our |t|<~5 revs;
//      deletes 256 dependent ops per lane-tile, shortens every sin chain.
//  (2) remove the cross-iter asm "memory" barrier: at VGPR 64/128-cap there is
//      headroom for the compiler to hoist next-tile loads into the L5 phase.
// Numerics: L1 fp32+split, L2 3-term, L3/L4/L5 hi-only RTE, omega folded into
// staged W1..W4/b1..b4, pkrtz only where lo captures residual.
// absmax expected ~0.0063-0.0068 (low-bit shift from sin reduction path).

typedef _Float16 f16x8 __attribute__((ext_vector_type(8)));
typedef __fp16 h16x2 __attribute__((ext_vector_type(2)));   // cvt_pkrtz return type
typedef float f32x4 __attribute__((ext_vector_type(4)));

#define MFMA16 __builtin_amdgcn_mfma_f32_16x16x32_f16

#define B_ 32
#define N_ 32768
#define NTHR 1024
#define NWAVE 16
#define OMEGA_SC 4.77464829275686f   /* 30 / (2*pi) */

// flat param offsets (floats)
#define OFF_W1 0
#define OFF_B1 256
#define OFF_W2 384
#define OFF_B2 16768
#define OFF_W3 16896
#define OFF_B3 33280
#define OFF_W4 33408
#define OFF_B4 49792
#define OFF_W5 49920
#define OFF_B5 50304
#define NPARAM 50307

// LDS image offsets (bytes). A-frag images: [c][mt][lane]*16B.
#define WO_L2H 0
#define WO_W2L 32768
#define WO_L3H 65536
#define WO_L4H 98304
#define WO_L5H 131072      /* 4 KB: single M-tile, rows 3..15 zero */
#define WO_W1X 135168      /* 128 floats, slot-ordered s = c*32 + k_local */
#define WO_W1Y 135680
#define WO_B1S 136192
#define LDS_BIAS 136704    /* 3*128 floats */
#define LDSSET 138240

// args arrive pre-scaled by OMEGA_SC (revolutions); v_sin_f32 HW-reduces,
// valid domain +-256 >> our |t| (<~5). No v_fract needed.
__device__ __forceinline__ float sin_rev(float t) {
    return __builtin_amdgcn_sinf(t);
}

__device__ __forceinline__ uint32_t pack2(_Float16 a, _Float16 b) {
    union { _Float16 h[2]; uint32_t u; } x;
    x.h[0] = a; x.h[1] = b;
    return x.u;
}

// sin pair -> hi/lo split packed via pkrtz (lo captures RTZ residual exactly)
__device__ __forceinline__ void sin_split_pk(float a0, float a1,
                                             uint32_t& hw, uint32_t& lw) {
    float s0 = sin_rev(a0), s1 = sin_rev(a1);
    union { h16x2 v; uint32_t u; } x, y;
    x.v = __builtin_amdgcn_cvt_pkrtz(s0, s1);
    float l0 = s0 - (float)x.v[0], l1 = s1 - (float)x.v[1];
    y.v = __builtin_amdgcn_cvt_pkrtz(l0, l1);
    hw = x.u; lw = y.u;
}

// ---------------------------------------------------------------------------
// Main: 1024 threads = 16 waves = 4 waves/SIMD, 1 block/CU (135 KB LDS).
// Phase 0 (fused prep): build LDS weight images directly from p, pre-scaled
//   by OMEGA_SC for the sine layers (W1..W4, b1..b4); W5/b5 unscaled.
//   16x16x32 A-frag: lane l holds A[m=16mt+(l&15)][k_local=8*(l>>4)+e];
//   feature f = 16c + 64*(e>=4) + 4g + (e&3). W2 stored hi+lo; W3/4/5 hi only.
// Phase 1: block covers a 4096-pt slab = 128 32-pt tiles; wave w takes tiles
//   w, w+16, ... (8 tiles each). Grid (32 batches, 8 slabs).
// ---------------------------------------------------------------------------
__global__ __launch_bounds__(NTHR, 4)
void siren_main(const float* __restrict__ xg,
                const float* __restrict__ pg,
                float* __restrict__ out) {
    extern __shared__ __align__(16) char smem[];

    const int t = threadIdx.x;
    const int b = blockIdx.x;
    const int grp = blockIdx.y;
    const float* p = pg + (size_t)b * NPARAM;

    // ---- fused prep: 102 u-slots x 64 lanes = 6528 items, wave-uniform u ----
    for (int it = t; it < 6528; it += NTHR) {
        const int u = it >> 6, l = it & 63;
        if (u < 100) {
            int li, c, mt;
            if (u < 96) { li = u >> 5; int r = u & 31; c = r >> 3; mt = r & 7; }
            else        { li = 3; c = u - 96; mt = 0; }
            const int m = l & 15, gA = l >> 4;
            int wOff; size_t dstH; bool lo = false;
            if (li == 0)      { wOff = OFF_W2; dstH = WO_L2H; lo = true; }
            else if (li == 1) { wOff = OFF_W3; dstH = WO_L3H; }
            else if (li == 2) { wOff = OFF_W4; dstH = WO_L4H; }
            else              { wOff = OFF_W5; dstH = WO_L5H; }
            const int j = (li == 3) ? m : (16 * mt + m);
            const int f0 = 16 * c + 4 * gA;
            const float sc = (li == 3) ? 1.0f : OMEGA_SC;   // W5 feeds no sine

            float v[8];
            if (li == 3 && m >= 3) {
#pragma unroll
                for (int e = 0; e < 8; ++e) v[e] = 0.f;
            } else {
                float4 a  = *(const float4*)(p + wOff + j * 128 + f0);
                float4 bq = *(const float4*)(p + wOff + j * 128 + f0 + 64);
                v[0] = sc * a.x;  v[1] = sc * a.y;  v[2] = sc * a.z;  v[3] = sc * a.w;
                v[4] = sc * bq.x; v[5] = sc * bq.y; v[6] = sc * bq.z; v[7] = sc * bq.w;
            }
            f16x8 hv, lv;
#pragma unroll
            for (int e = 0; e < 8; ++e) {
                _Float16 hh = (_Float16)v[e];
                hv[e] = hh;
                lv[e] = (_Float16)(v[e] - (float)hh);
            }
            size_t idx = (li == 3) ? (size_t)(c * 64 + l) * 16
                                   : (size_t)((c * 8 + mt) * 64 + l) * 16;
            *(f16x8*)(smem + dstH + idx) = hv;
            if (lo) *(f16x8*)(smem + WO_W2L + idx) = lv;
        } else {
            int s = ((u - 100) << 6) + l;      // 0..127
            int c = s >> 5, k = s & 31, gq = k >> 3, e = k & 7;
            int f = 16 * c + ((e & 4) ? 64 : 0) + 4 * gq + (e & 3);
            ((float*)(smem + WO_W1X))[s] = OMEGA_SC * p[OFF_W1 + 2 * f];
            ((float*)(smem + WO_W1Y))[s] = OMEGA_SC * p[OFF_W1 + 2 * f + 1];
            ((float*)(smem + WO_B1S))[s] = OMEGA_SC * p[OFF_B1 + f];
        }
    }
    float* sB = (float*)(smem + LDS_BIAS);
    if (t < 384) {
        int li = t >> 7, f = t & 127;
        sB[t] = OMEGA_SC * p[(li == 0 ? OFF_B2 : li == 1 ? OFF_B3 : OFF_B4) + f];
    }
    const float b5_0 = p[OFF_B5], b5_1 = p[OFF_B5 + 1], b5_2 = p[OFF_B5 + 2];
    __syncthreads();

    const int lane = t & 63;
    const int wv = t >> 6;          // 0..15
    const int n = lane & 15;
    const int g = lane >> 4;
    const int lb = lane * 16;

    const char* L2Hp = smem + WO_L2H;
    const char* W2Lp = smem + WO_W2L;
    const char* L3Hp = smem + WO_L3H;
    const char* L4Hp = smem + WO_L4H;
    const char* L5Hp = smem + WO_L5H;
    const float* W1X = (const float*)(smem + WO_W1X);
    const float* W1Y = (const float*)(smem + WO_W1Y);
    const float* B1S = (const float*)(smem + WO_B1S);

    union UF { f16x8 v; uint32_t w[4]; };

    auto initb2 = [&](f32x4 (&A)[2][8], int li) {
#pragma unroll
        for (int mt = 0; mt < 8; ++mt) {
            f32x4 bb = *(const f32x4*)&sB[li * 128 + 16 * mt + 4 * g];
            A[0][mt] = bb;
            A[1][mt] = bb;
        }
    };

    // acc -> B-frag chunk c = {tile c regs 0-3 (e0-3), tile c+4 regs 0-3 (e4-7)}
    // RTE converts (hi-only: RTZ bias would inject sign-correlated error)
    auto epi_hi2 = [&](const f32x4 (&A)[2][8], UF (&Xh)[2][4]) {
#pragma unroll
        for (int pp = 0; pp < 2; ++pp)
#pragma unroll
            for (int c = 0; c < 4; ++c) {
                _Float16 hh[8];
#pragma unroll
                for (int r = 0; r < 4; ++r) {
                    hh[r]     = (_Float16)sin_rev(A[pp][c][r]);
                    hh[4 + r] = (_Float16)sin_rev(A[pp][c + 4][r]);
                }
                Xh[pp][c].w[0] = pack2(hh[0], hh[1]); Xh[pp][c].w[1] = pack2(hh[2], hh[3]);
                Xh[pp][c].w[2] = pack2(hh[4], hh[5]); Xh[pp][c].w[3] = pack2(hh[6], hh[7]);
            }
    };

#pragma unroll 1
    for (int tile = wv; tile < 128; tile += NWAVE) {
        const int ptb = grp * 4096 + tile * 32;
        const float2 xy0 = ((const float2*)xg)[(size_t)b * N_ + ptb + n];
        const float2 xy1 = ((const float2*)xg)[(size_t)b * N_ + ptb + 16 + n];

        // ---- L1+L2 fused per c-chunk (r16): produce X1h/l[.][c], consume in
        //      L2 c-pass; L1(c+1) VALU interleaves with in-flight MFMA(c).
        f32x4 A2[2][8];
        initb2(A2, 0);
#pragma unroll
        for (int c = 0; c < 4; ++c) {
            UF X1h[2], X1l[2];
            {
                const int s0 = c * 32 + g * 8;
                float4 wxa = *(const float4*)(W1X + s0), wxb = *(const float4*)(W1X + s0 + 4);
                float4 wya = *(const float4*)(W1Y + s0), wyb = *(const float4*)(W1Y + s0 + 4);
                float4 bba = *(const float4*)(B1S + s0), bbb = *(const float4*)(B1S + s0 + 4);
                float wx[8] = {wxa.x, wxa.y, wxa.z, wxa.w, wxb.x, wxb.y, wxb.z, wxb.w};
                float wy[8] = {wya.x, wya.y, wya.z, wya.w, wyb.x, wyb.y, wyb.z, wyb.w};
                float bc[8] = {bba.x, bba.y, bba.z, bba.w, bbb.x, bbb.y, bbb.z, bbb.w};
#pragma unroll
                for (int pp = 0; pp < 2; ++pp) {
                    const float px = pp ? xy1.x : xy0.x;
                    const float py = pp ? xy1.y : xy0.y;
                    float a[8];
#pragma unroll
                    for (int e = 0; e < 8; ++e)
                        a[e] = fmaf(px, wx[e], fmaf(py, wy[e], bc[e]));
                    sin_split_pk(a[0], a[1], X1h[pp].w[0], X1l[pp].w[0]);
                    sin_split_pk(a[2], a[3], X1h[pp].w[1], X1l[pp].w[1]);
                    sin_split_pk(a[4], a[5], X1h[pp].w[2], X1l[pp].w[2]);
                    sin_split_pk(a[6], a[7], X1h[pp].w[3], X1l[pp].w[3]);
                }
            }
            __builtin_amdgcn_s_setprio(1);
#pragma unroll
            for (int mt = 0; mt < 8; ++mt) {
                f16x8 ah = *(const f16x8*)(L2Hp + (c * 8 + mt) * 1024 + lb);
                f16x8 al = *(const f16x8*)(W2Lp + (c * 8 + mt) * 1024 + lb);
#pragma unroll
                for (int pp = 0; pp < 2; ++pp) {
                    A2[pp][mt] = MFMA16(ah, X1h[pp].v, A2[pp][mt], 0, 0, 0);
                    A2[pp][mt] = MFMA16(ah, X1l[pp].v, A2[pp][mt], 0, 0, 0);
                    A2[pp][mt] = MFMA16(al, X1h[pp].v, A2[pp][mt], 0, 0, 0);
                }
            }
            __builtin_amdgcn_s_setprio(0);
        }

        UF X2h[2][4];
        epi_hi2(A2, X2h);

        // ---- L3: 1-term (X2 hi only; RTE-packed above)
        f32x4 A3[2][8];
        initb2(A3, 1);
        __builtin_amdgcn_s_setprio(1);
#pragma unroll
        for (int c = 0; c < 4; ++c)
#pragma unroll
            for (int mt = 0; mt < 8; ++mt) {
                f16x8 ah = *(const f16x8*)(L3Hp + (c * 8 + mt) * 1024 + lb);
#pragma unroll
                for (int pp = 0; pp < 2; ++pp)
                    A3[pp][mt] = MFMA16(ah, X2h[pp][c].v, A3[pp][mt], 0, 0, 0);
            }
        __builtin_amdgcn_s_setprio(0);

        UF X3h[2][4];
        epi_hi2(A3, X3h);

        // ---- L4: plain f16
        f32x4 A4[2][8];
        initb2(A4, 2);
        __builtin_amdgcn_s_setprio(1);
#pragma unroll
        for (int c = 0; c < 4; ++c)
#pragma unroll
            for (int mt = 0; mt < 8; ++mt) {
                f16x8 ah = *(const f16x8*)(L4Hp + (c * 8 + mt) * 1024 + lb);
#pragma unroll
                for (int pp = 0; pp < 2; ++pp)
                    A4[pp][mt] = MFMA16(ah, X3h[pp][c].v, A4[pp][mt], 0, 0, 0);
            }
        __builtin_amdgcn_s_setprio(0);

        UF X4h[2][4];
        epi_hi2(A4, X4h);

        // ---- L5: single M-padded tile per point-tile (unscaled weights)
        f32x4 a5[2] = {{0.f, 0.f, 0.f, 0.f}, {0.f, 0.f, 0.f, 0.f}};
        __builtin_amdgcn_s_setprio(1);
#pragma unroll
        for (int c = 0; c < 4; ++c) {
            f16x8 ah = *(const f16x8*)(L5Hp + c * 1024 + lb);
#pragma unroll
            for (int pp = 0; pp < 2; ++pp)
                a5[pp] = MFMA16(ah, X4h[pp][c].v, a5[pp], 0, 0, 0);
        }
        __builtin_amdgcn_s_setprio(0);

        if (g == 0) {   // rows 0..2 = outputs j=0..2 for point n
#pragma unroll
            for (int pp = 0; pp < 2; ++pp) {
                size_t o = ((size_t)b * N_ + ptb + pp * 16 + n) * 3;
                out[o]     = a5[pp][0] + b5_0;
                out[o + 1] = a5[pp][1] + b5_1;
                out[o + 2] = a5[pp][2] + b5_2;
            }
        }
    }
}

extern "C" void kernel_launch(void* const* d_in, const int* in_sizes, int n_in,
                              void* d_out, int out_size, void* d_ws, size_t ws_size,
                              hipStream_t stream) {
    (void)in_sizes; (void)n_in; (void)out_size; (void)d_ws; (void)ws_size;
    const float* x = (const float*)d_in[0];
    const float* p = (const float*)d_in[1];
    float* o = (float*)d_out;

    // Raise the dynamic-LDS cap exactly once (not per graph-capture pass).
    static bool attr_done = false;
    if (!attr_done) {
        (void)hipFuncSetAttribute(reinterpret_cast<const void*>(siren_main),
                                  hipFuncAttributeMaxDynamicSharedMemorySize, LDSSET);
        attr_done = true;
    }
    siren_main<<<dim3(32, 8), NTHR, LDSSET, stream>>>(x, p, o);
}

// Round 9
// 198.511 us; speedup vs baseline: 1.1668x; 1.0356x over previous
//
#include <hip/hip_runtime.h>
#include <stdint.h>

// SIREN batched MLP, MI355X/gfx950 — round 20: r18 base + pkrtz epilogue.
// r19 FAILED numerics (absmax 0.0200 > threshold 0.0167): W2-lo correction is
// indispensable (~0.019 error alone). 3-term L2 restored verbatim.
// Learned: threshold = 0.0167, full-precision absmax = 0.0063 -> 2.6x margin.
// r20 spends a little margin on VALU: epi converts sin pairs with ONE
// v_cvt_pkrtz_f16_f32 (pack+convert) instead of 2x v_cvt_f16_f32 + pack:
// 96 pkrtz replaces ~288 ops per tile-lane (~384 cy saved). RTZ adds <=1 ulp
// (4.9e-4) per activation; expected absmax ~0.008-0.012 < 0.0167.
// If failed -> revert epi to RTE scalar (exact r18) next round.
// Base numerics: L1 fp32+split, L2 3-term hi/lo, L3/L4/L5 hi-only, omega
// folded into staged W1..W4/b1..b4, no v_fract, no cross-iter barrier.

typedef _Float16 f16x8 __attribute__((ext_vector_type(8)));
typedef __fp16 h16x2 __attribute__((ext_vector_type(2)));   // cvt_pkrtz return type
typedef float f32x4 __attribute__((ext_vector_type(4)));

#define MFMA16 __builtin_amdgcn_mfma_f32_16x16x32_f16

#define B_ 32
#define N_ 32768
#define NTHR 1024
#define NWAVE 16
#define OMEGA_SC 4.77464829275686f   /* 30 / (2*pi) */

// flat param offsets (floats)
#define OFF_W1 0
#define OFF_B1 256
#define OFF_W2 384
#define OFF_B2 16768
#define OFF_W3 16896
#define OFF_B3 33280
#define OFF_W4 33408
#define OFF_B4 49792
#define OFF_W5 49920
#define OFF_B5 50304
#define NPARAM 50307

// LDS image offsets (bytes). A-frag images: [c][mt][lane]*16B.
#define WO_L2H 0
#define WO_W2L 32768
#define WO_L3H 65536
#define WO_L4H 98304
#define WO_L5H 131072      /* 4 KB: single M-tile, rows 3..15 zero */
#define WO_W1X 135168      /* 128 floats, slot-ordered s = c*32 + k_local */
#define WO_W1Y 135680
#define WO_B1S 136192
#define LDS_BIAS 136704    /* 3*128 floats */
#define LDSSET 138240

// args arrive pre-scaled by OMEGA_SC (revolutions); v_sin_f32 HW-reduces.
__device__ __forceinline__ float sin_rev(float t) {
    return __builtin_amdgcn_sinf(t);
}

__device__ __forceinline__ uint32_t pkrtz_u32(float a, float b) {
    union { h16x2 v; uint32_t u; } x;
    x.v = __builtin_amdgcn_cvt_pkrtz(a, b);
    return x.u;
}

// sin pair -> hi/lo split packed via pkrtz (lo captures RTZ residual exactly)
__device__ __forceinline__ void sin_split_pk(float a0, float a1,
                                             uint32_t& hw, uint32_t& lw) {
    float s0 = sin_rev(a0), s1 = sin_rev(a1);
    union { h16x2 v; uint32_t u; } x, y;
    x.v = __builtin_amdgcn_cvt_pkrtz(s0, s1);
    float l0 = s0 - (float)x.v[0], l1 = s1 - (float)x.v[1];
    y.v = __builtin_amdgcn_cvt_pkrtz(l0, l1);
    hw = x.u; lw = y.u;
}

// ---------------------------------------------------------------------------
// Main: 1024 threads = 16 waves = 4 waves/SIMD, 1 block/CU (135 KB LDS).
// Phase 0 (fused prep): build LDS weight images directly from p, pre-scaled
//   by OMEGA_SC for the sine layers (W1..W4, b1..b4); W5/b5 unscaled.
//   16x16x32 A-frag: lane l holds A[m=16mt+(l&15)][k_local=8*(l>>4)+e];
//   feature f = 16c + 64*(e>=4) + 4g + (e&3). W2 stored hi+lo; W3/4/5 hi only.
// Phase 1: block covers a 4096-pt slab = 128 32-pt tiles; wave w takes tiles
//   w, w+16, ... (8 tiles each). Grid (32 batches, 8 slabs).
// ---------------------------------------------------------------------------
__global__ __launch_bounds__(NTHR, 4)
void siren_main(const float* __restrict__ xg,
                const float* __restrict__ pg,
                float* __restrict__ out) {
    extern __shared__ __align__(16) char smem[];

    const int t = threadIdx.x;
    const int b = blockIdx.x;
    const int grp = blockIdx.y;
    const float* p = pg + (size_t)b * NPARAM;

    // ---- fused prep: 102 u-slots x 64 lanes = 6528 items, wave-uniform u ----
    for (int it = t; it < 6528; it += NTHR) {
        const int u = it >> 6, l = it & 63;
        if (u < 100) {
            int li, c, mt;
            if (u < 96) { li = u >> 5; int r = u & 31; c = r >> 3; mt = r & 7; }
            else        { li = 3; c = u - 96; mt = 0; }
            const int m = l & 15, gA = l >> 4;
            int wOff; size_t dstH; bool lo = false;
            if (li == 0)      { wOff = OFF_W2; dstH = WO_L2H; lo = true; }
            else if (li == 1) { wOff = OFF_W3; dstH = WO_L3H; }
            else if (li == 2) { wOff = OFF_W4; dstH = WO_L4H; }
            else              { wOff = OFF_W5; dstH = WO_L5H; }
            const int j = (li == 3) ? m : (16 * mt + m);
            const int f0 = 16 * c + 4 * gA;
            const float sc = (li == 3) ? 1.0f : OMEGA_SC;   // W5 feeds no sine

            float v[8];
            if (li == 3 && m >= 3) {
#pragma unroll
                for (int e = 0; e < 8; ++e) v[e] = 0.f;
            } else {
                float4 a  = *(const float4*)(p + wOff + j * 128 + f0);
                float4 bq = *(const float4*)(p + wOff + j * 128 + f0 + 64);
                v[0] = sc * a.x;  v[1] = sc * a.y;  v[2] = sc * a.z;  v[3] = sc * a.w;
                v[4] = sc * bq.x; v[5] = sc * bq.y; v[6] = sc * bq.z; v[7] = sc * bq.w;
            }
            f16x8 hv, lv;
#pragma unroll
            for (int e = 0; e < 8; ++e) {
                _Float16 hh = (_Float16)v[e];
                hv[e] = hh;
                lv[e] = (_Float16)(v[e] - (float)hh);
            }
            size_t idx = (li == 3) ? (size_t)(c * 64 + l) * 16
                                   : (size_t)((c * 8 + mt) * 64 + l) * 16;
            *(f16x8*)(smem + dstH + idx) = hv;
            if (lo) *(f16x8*)(smem + WO_W2L + idx) = lv;
        } else {
            int s = ((u - 100) << 6) + l;      // 0..127
            int c = s >> 5, k = s & 31, gq = k >> 3, e = k & 7;
            int f = 16 * c + ((e & 4) ? 64 : 0) + 4 * gq + (e & 3);
            ((float*)(smem + WO_W1X))[s] = OMEGA_SC * p[OFF_W1 + 2 * f];
            ((float*)(smem + WO_W1Y))[s] = OMEGA_SC * p[OFF_W1 + 2 * f + 1];
            ((float*)(smem + WO_B1S))[s] = OMEGA_SC * p[OFF_B1 + f];
        }
    }
    float* sB = (float*)(smem + LDS_BIAS);
    if (t < 384) {
        int li = t >> 7, f = t & 127;
        sB[t] = OMEGA_SC * p[(li == 0 ? OFF_B2 : li == 1 ? OFF_B3 : OFF_B4) + f];
    }
    const float b5_0 = p[OFF_B5], b5_1 = p[OFF_B5 + 1], b5_2 = p[OFF_B5 + 2];
    __syncthreads();

    const int lane = t & 63;
    const int wv = t >> 6;          // 0..15
    const int n = lane & 15;
    const int g = lane >> 4;
    const int lb = lane * 16;

    const char* L2Hp = smem + WO_L2H;
    const char* W2Lp = smem + WO_W2L;
    const char* L3Hp = smem + WO_L3H;
    const char* L4Hp = smem + WO_L4H;
    const char* L5Hp = smem + WO_L5H;
    const float* W1X = (const float*)(smem + WO_W1X);
    const float* W1Y = (const float*)(smem + WO_W1Y);
    const float* B1S = (const float*)(smem + WO_B1S);

    union UF { f16x8 v; uint32_t w[4]; };

    auto initb2 = [&](f32x4 (&A)[2][8], int li) {
#pragma unroll
        for (int mt = 0; mt < 8; ++mt) {
            f32x4 bb = *(const f32x4*)&sB[li * 128 + 16 * mt + 4 * g];
            A[0][mt] = bb;
            A[1][mt] = bb;
        }
    };

    // acc -> B-frag chunk c = {tile c regs 0-3 (e0-3), tile c+4 regs 0-3 (e4-7)}
    // r20: pair-convert+pack in ONE v_cvt_pkrtz_f16_f32 (RTZ; ~190 fewer VALU
    // ops per tile-lane than scalar RTE cvt + pack).
    auto epi_hi2 = [&](const f32x4 (&A)[2][8], UF (&Xh)[2][4]) {
#pragma unroll
        for (int pp = 0; pp < 2; ++pp)
#pragma unroll
            for (int c = 0; c < 4; ++c) {
                float s[8];
#pragma unroll
                for (int r = 0; r < 4; ++r) {
                    s[r]     = sin_rev(A[pp][c][r]);
                    s[4 + r] = sin_rev(A[pp][c + 4][r]);
                }
                Xh[pp][c].w[0] = pkrtz_u32(s[0], s[1]);
                Xh[pp][c].w[1] = pkrtz_u32(s[2], s[3]);
                Xh[pp][c].w[2] = pkrtz_u32(s[4], s[5]);
                Xh[pp][c].w[3] = pkrtz_u32(s[6], s[7]);
            }
    };

#pragma unroll 1
    for (int tile = wv; tile < 128; tile += NWAVE) {
        const int ptb = grp * 4096 + tile * 32;
        const float2 xy0 = ((const float2*)xg)[(size_t)b * N_ + ptb + n];
        const float2 xy1 = ((const float2*)xg)[(size_t)b * N_ + ptb + 16 + n];

        // ---- L1+L2 fused per c-chunk (r16): produce X1h/l[.][c], consume in
        //      L2 c-pass; L1(c+1) VALU interleaves with in-flight MFMA(c).
        f32x4 A2[2][8];
        initb2(A2, 0);
#pragma unroll
        for (int c = 0; c < 4; ++c) {
            UF X1h[2], X1l[2];
            {
                const int s0 = c * 32 + g * 8;
                float4 wxa = *(const float4*)(W1X + s0), wxb = *(const float4*)(W1X + s0 + 4);
                float4 wya = *(const float4*)(W1Y + s0), wyb = *(const float4*)(W1Y + s0 + 4);
                float4 bba = *(const float4*)(B1S + s0), bbb = *(const float4*)(B1S + s0 + 4);
                float wx[8] = {wxa.x, wxa.y, wxa.z, wxa.w, wxb.x, wxb.y, wxb.z, wxb.w};
                float wy[8] = {wya.x, wya.y, wya.z, wya.w, wyb.x, wyb.y, wyb.z, wyb.w};
                float bc[8] = {bba.x, bba.y, bba.z, bba.w, bbb.x, bbb.y, bbb.z, bbb.w};
#pragma unroll
                for (int pp = 0; pp < 2; ++pp) {
                    const float px = pp ? xy1.x : xy0.x;
                    const float py = pp ? xy1.y : xy0.y;
                    float a[8];
#pragma unroll
                    for (int e = 0; e < 8; ++e)
                        a[e] = fmaf(px, wx[e], fmaf(py, wy[e], bc[e]));
                    sin_split_pk(a[0], a[1], X1h[pp].w[0], X1l[pp].w[0]);
                    sin_split_pk(a[2], a[3], X1h[pp].w[1], X1l[pp].w[1]);
                    sin_split_pk(a[4], a[5], X1h[pp].w[2], X1l[pp].w[2]);
                    sin_split_pk(a[6], a[7], X1h[pp].w[3], X1l[pp].w[3]);
                }
            }
            __builtin_amdgcn_s_setprio(1);
#pragma unroll
            for (int mt = 0; mt < 8; ++mt) {
                f16x8 ah = *(const f16x8*)(L2Hp + (c * 8 + mt) * 1024 + lb);
                f16x8 al = *(const f16x8*)(W2Lp + (c * 8 + mt) * 1024 + lb);
#pragma unroll
                for (int pp = 0; pp < 2; ++pp) {
                    A2[pp][mt] = MFMA16(ah, X1h[pp].v, A2[pp][mt], 0, 0, 0);
                    A2[pp][mt] = MFMA16(ah, X1l[pp].v, A2[pp][mt], 0, 0, 0);
                    A2[pp][mt] = MFMA16(al, X1h[pp].v, A2[pp][mt], 0, 0, 0);
                }
            }
            __builtin_amdgcn_s_setprio(0);
        }

        UF X2h[2][4];
        epi_hi2(A2, X2h);

        // ---- L3: 1-term (X2 hi only)
        f32x4 A3[2][8];
        initb2(A3, 1);
        __builtin_amdgcn_s_setprio(1);
#pragma unroll
        for (int c = 0; c < 4; ++c)
#pragma unroll
            for (int mt = 0; mt < 8; ++mt) {
                f16x8 ah = *(const f16x8*)(L3Hp + (c * 8 + mt) * 1024 + lb);
#pragma unroll
                for (int pp = 0; pp < 2; ++pp)
                    A3[pp][mt] = MFMA16(ah, X2h[pp][c].v, A3[pp][mt], 0, 0, 0);
            }
        __builtin_amdgcn_s_setprio(0);

        UF X3h[2][4];
        epi_hi2(A3, X3h);

        // ---- L4: plain f16
        f32x4 A4[2][8];
        initb2(A4, 2);
        __builtin_amdgcn_s_setprio(1);
#pragma unroll
        for (int c = 0; c < 4; ++c)
#pragma unroll
            for (int mt = 0; mt < 8; ++mt) {
                f16x8 ah = *(const f16x8*)(L4Hp + (c * 8 + mt) * 1024 + lb);
#pragma unroll
                for (int pp = 0; pp < 2; ++pp)
                    A4[pp][mt] = MFMA16(ah, X3h[pp][c].v, A4[pp][mt], 0, 0, 0);
            }
        __builtin_amdgcn_s_setprio(0);

        UF X4h[2][4];
        epi_hi2(A4, X4h);

        // ---- L5: single M-padded tile per point-tile (unscaled weights)
        f32x4 a5[2] = {{0.f, 0.f, 0.f, 0.f}, {0.f, 0.f, 0.f, 0.f}};
        __builtin_amdgcn_s_setprio(1);
#pragma unroll
        for (int c = 0; c < 4; ++c) {
            f16x8 ah = *(const f16x8*)(L5Hp + c * 1024 + lb);
#pragma unroll
            for (int pp = 0; pp < 2; ++pp)
                a5[pp] = MFMA16(ah, X4h[pp][c].v, a5[pp], 0, 0, 0);
        }
        __builtin_amdgcn_s_setprio(0);

        if (g == 0) {   // rows 0..2 = outputs j=0..2 for point n
#pragma unroll
            for (int pp = 0; pp < 2; ++pp) {
                size_t o = ((size_t)b * N_ + ptb + pp * 16 + n) * 3;
                out[o]     = a5[pp][0] + b5_0;
                out[o + 1] = a5[pp][1] + b5_1;
                out[o + 2] = a5[pp][2] + b5_2;
            }
        }
    }
}

extern "C" void kernel_launch(void* const* d_in, const int* in_sizes, int n_in,
                              void* d_out, int out_size, void* d_ws, size_t ws_size,
                              hipStream_t stream) {
    (void)in_sizes; (void)n_in; (void)out_size; (void)d_ws; (void)ws_size;
    const float* x = (const float*)d_in[0];
    const float* p = (const float*)d_in[1];
    float* o = (float*)d_out;

    // Raise the dynamic-LDS cap exactly once (not per graph-capture pass).
    static bool attr_done = false;
    if (!attr_done) {
        (void)hipFuncSetAttribute(reinterpret_cast<const void*>(siren_main),
                                  hipFuncAttributeMaxDynamicSharedMemorySize, LDSSET);
        attr_done = true;
    }
    siren_main<<<dim3(32, 8), NTHR, LDSSET, stream>>>(x, p, o);
}